// Round 1
// 989.893 us; speedup vs baseline: 1.0139x; 1.0139x over previous
//
#include <hip/hip_runtime.h>

// E2V layer, decomposed:
//   proj[e][0:64]   = hyperedge[e] @ W0^T + b      (precomputed per edge, f32, in d_ws)
//   proj[e][64:128] = hyperedge[e] @ W1^T
//   out[n] = relu( proj[i0[n]][0:64] + proj[i1[n]][64:128] + node[n] @ W2^T )
// Main kernel: transposed MFMA (W as A-operand) so each lane holds 4 consecutive
// output channels -> dwordx4 gathers + dwordx4 stores. aff indices prefetched 1 tile ahead.

typedef __bf16 bf16x8 __attribute__((ext_vector_type(8)));
typedef float  f32x4  __attribute__((ext_vector_type(4)));

static __device__ __forceinline__ bf16x8 cvt8(f32x4 a, f32x4 b) {
  bf16x8 r;
  r[0] = (__bf16)a[0]; r[1] = (__bf16)a[1]; r[2] = (__bf16)a[2]; r[3] = (__bf16)a[3];
  r[4] = (__bf16)b[0]; r[5] = (__bf16)b[1]; r[6] = (__bf16)b[2]; r[7] = (__bf16)b[3];
  return r;
}

static __device__ __forceinline__ bf16x8 load_frag(const float* __restrict__ p) {
  f32x4 a = *(const f32x4*)p;
  f32x4 b = *(const f32x4*)(p + 4);
  return cvt8(a, b);
}

#define N_EDGES  100000
#define N_INC    2000000
#define N_TILES  (N_INC / 16)    // 125000
#define E_TILES  (N_EDGES / 16)  // 6250

// ---------------------------------------------------------------------------
// Kernel 1: per-edge projections. proj row layout: [128] = [W0-part+bias | W1-part]
// Transposed MFMA: A = W rows (channel block), B = he^T. D: row=channel, col=edge.
// ---------------------------------------------------------------------------
__global__ __launch_bounds__(256, 2) void edge_proj(
    const float* __restrict__ hyperedge,  // [100000, 64]
    const float* __restrict__ W,          // [64, 192]
    const float* __restrict__ bias,       // [64]
    float*       __restrict__ proj)       // [100000, 128]
{
  const int lane = threadIdx.x & 63;
  const int wid  = (blockIdx.x * blockDim.x + threadIdx.x) >> 6;
  if (wid >= E_TILES) return;
  const int m    = lane & 15;
  const int quad = lane >> 4;
  const int koff = quad * 8;

  // A-operand fragments: Wf[t][f], t=0..3 -> W0 rows t*16+m, t=4..7 -> W1 rows (t-4)*16+m
  bf16x8 Wf[8][2];
  #pragma unroll
  for (int t = 0; t < 8; ++t) {
    const float* wr = W + (long)((t & 3) * 16 + m) * 192 + (t >> 2) * 64 + koff;
    #pragma unroll
    for (int f = 0; f < 2; ++f)
      Wf[t][f] = load_frag(wr + f * 32);
  }

  const int ebase = wid * 16;
  const float* er = hyperedge + (long)(ebase + m) * 64 + koff;
  bf16x8 hef0 = load_frag(er);
  bf16x8 hef1 = load_frag(er + 32);

  f32x4 acc[8] = { {0,0,0,0},{0,0,0,0},{0,0,0,0},{0,0,0,0},
                   {0,0,0,0},{0,0,0,0},{0,0,0,0},{0,0,0,0} };
  #pragma unroll
  for (int t = 0; t < 8; ++t) {
    acc[t] = __builtin_amdgcn_mfma_f32_16x16x32_bf16(Wf[t][0], hef0, acc[t], 0, 0, 0);
    acc[t] = __builtin_amdgcn_mfma_f32_16x16x32_bf16(Wf[t][1], hef1, acc[t], 0, 0, 0);
  }

  // D: col = lane&15 = edge within tile, row = quad*4+r = channel within 16-block
  float* pr = proj + (long)(ebase + m) * 128 + quad * 4;
  #pragma unroll
  for (int t = 0; t < 8; ++t) {
    f32x4 v = acc[t];
    if (t < 4) {
      f32x4 bv = *(const f32x4*)(bias + t * 16 + quad * 4);
      v[0] += bv[0]; v[1] += bv[1]; v[2] += bv[2]; v[3] += bv[3];
    }
    *(f32x4*)(pr + t * 16) = v;
  }
}

// ---------------------------------------------------------------------------
// Kernel 2: main. Per 16-incidence tile: node@W2^T via transposed MFMA,
// add gathered proj rows, relu, dwordx4 stores.
// ---------------------------------------------------------------------------
__global__ __launch_bounds__(256, 4) void e2v_gather(
    const float* __restrict__ hyper_node, // [N_INC, 64]
    const int*   __restrict__ aff,        // [2, N_INC]
    const float* __restrict__ W,          // [64, 192]
    const float* __restrict__ proj,       // [100000, 128]
    float*       __restrict__ out)        // [N_INC, 64]
{
  const int lane = threadIdx.x & 63;
  const int wid  = (blockIdx.x * blockDim.x + threadIdx.x) >> 6;
  const int nw   = (gridDim.x * blockDim.x) >> 6;
  const int m    = lane & 15;
  const int quad = lane >> 4;
  const int koff = quad * 8;

  // A-operand: W2 rows (channel blocks). W2[c][k] = W[c][128+k]
  bf16x8 Wf2[4][2];
  #pragma unroll
  for (int t = 0; t < 4; ++t) {
    const float* wr = W + (long)(t * 16 + m) * 192 + 128 + koff;
    #pragma unroll
    for (int f = 0; f < 2; ++f)
      Wf2[t][f] = load_frag(wr + f * 32);
  }

  const int* __restrict__ aff0 = aff;
  const int* __restrict__ aff1 = aff + N_INC;

  int tile = wid;
  if (tile >= N_TILES) return;

  // prefetched indices for the current tile
  int ni0 = aff0[tile * 16 + m];
  int ni1 = aff1[tile * 16 + m];

  for (; tile < N_TILES; tile += nw) {
    const int i0 = ni0;
    const int i1 = ni1;
    const int nb = tile * 16;

    // prefetch next tile's indices (breaks the aff->gather serial chain)
    const int nt = tile + nw;
    if (nt < N_TILES) {
      ni0 = aff0[nt * 16 + m];
      ni1 = aff1[nt * 16 + m];
    }

    // gathers: per instruction, 16 rows x 64B contiguous chunks
    const float* p0 = proj + (long)i0 * 128 + quad * 4;
    const float* p1 = proj + (long)i1 * 128 + 64 + quad * 4;
    f32x4 g0[4], g1[4];
    #pragma unroll
    for (int t = 0; t < 4; ++t) {
      g0[t] = *(const f32x4*)(p0 + t * 16);
      g1[t] = *(const f32x4*)(p1 + t * 16);
    }

    // node fragments (B-operand: col = incidence m)
    const float* nd = hyper_node + (long)(nb + m) * 64 + koff;
    bf16x8 Nf0 = load_frag(nd);
    bf16x8 Nf1 = load_frag(nd + 32);

    f32x4 acc[4] = { {0,0,0,0},{0,0,0,0},{0,0,0,0},{0,0,0,0} };
    #pragma unroll
    for (int t = 0; t < 4; ++t)
      acc[t] = __builtin_amdgcn_mfma_f32_16x16x32_bf16(Wf2[t][0], Nf0, acc[t], 0, 0, 0);
    #pragma unroll
    for (int t = 0; t < 4; ++t)
      acc[t] = __builtin_amdgcn_mfma_f32_16x16x32_bf16(Wf2[t][1], Nf1, acc[t], 0, 0, 0);

    // D: col = lane&15 = incidence, row = quad*4+r = channel within t-block
    float* op = out + (long)(nb + m) * 64 + quad * 4;
    #pragma unroll
    for (int t = 0; t < 4; ++t) {
      f32x4 v;
      #pragma unroll
      for (int r = 0; r < 4; ++r) {
        float x = acc[t][r] + g0[t][r] + g1[t][r];
        v[r] = x > 0.f ? x : 0.f;
      }
      *(f32x4*)(op + t * 16) = v;
    }
  }
}

// ---------------------------------------------------------------------------
// Fallback (previous best, fused 192-K): used only if workspace is too small.
// ---------------------------------------------------------------------------
__global__ __launch_bounds__(256, 2) void e2v_mfma(
    const float* __restrict__ hyperedge,
    const float* __restrict__ hyper_node,
    const int*   __restrict__ aff,
    const float* __restrict__ W,
    const float* __restrict__ bias,
    float*       __restrict__ out)
{
  const int lane = threadIdx.x & 63;
  const int wid  = (blockIdx.x * blockDim.x + threadIdx.x) >> 6;
  const int nw   = (gridDim.x * blockDim.x) >> 6;
  const int m    = lane & 15;
  const int quad = lane >> 4;
  const int koff = quad * 8;

  bf16x8 Bf[4][6];
  #pragma unroll
  for (int t = 0; t < 4; ++t) {
    const float* wr = W + (t * 16 + m) * 192 + koff;
    #pragma unroll
    for (int f = 0; f < 6; ++f)
      Bf[t][f] = load_frag(wr + f * 32);
  }
  float bv[4];
  #pragma unroll
  for (int t = 0; t < 4; ++t) bv[t] = bias[t * 16 + m];

  const int* __restrict__ aff0 = aff;
  const int* __restrict__ aff1 = aff + N_INC;

  for (int tile = wid; tile < N_TILES; tile += nw) {
    const int n_base = tile * 16;
    const int i0 = aff0[n_base + m];
    const int i1 = aff1[n_base + m];
    const float* e0 = hyperedge  + (long)i0 * 64 + koff;
    const float* e1 = hyperedge  + (long)i1 * 64 + koff;
    const float* nd = hyper_node + (long)(n_base + m) * 64 + koff;

    bf16x8 A[6];
    A[0] = load_frag(e0);
    A[1] = load_frag(e0 + 32);
    A[2] = load_frag(e1);
    A[3] = load_frag(e1 + 32);
    A[4] = load_frag(nd);
    A[5] = load_frag(nd + 32);

    f32x4 acc[4] = { {0.f,0.f,0.f,0.f}, {0.f,0.f,0.f,0.f},
                     {0.f,0.f,0.f,0.f}, {0.f,0.f,0.f,0.f} };
    #pragma unroll
    for (int f = 0; f < 6; ++f) {
      #pragma unroll
      for (int t = 0; t < 4; ++t)
        acc[t] = __builtin_amdgcn_mfma_f32_16x16x32_bf16(A[f], Bf[t][f], acc[t], 0, 0, 0);
    }

    #pragma unroll
    for (int t = 0; t < 4; ++t) {
      const int o = t * 16 + m;
      #pragma unroll
      for (int r = 0; r < 4; ++r) {
        const int inc = n_base + quad * 4 + r;
        float v = acc[t][r] + bv[t];
        out[(long)inc * 64 + o] = v > 0.f ? v : 0.f;
      }
    }
  }
}

extern "C" void kernel_launch(void* const* d_in, const int* in_sizes, int n_in,
                              void* d_out, int out_size, void* d_ws, size_t ws_size,
                              hipStream_t stream) {
  const float* hyperedge  = (const float*)d_in[0];
  const float* hyper_node = (const float*)d_in[1];
  const int*   aff        = (const int*)d_in[2];
  const float* W          = (const float*)d_in[3];
  const float* bias       = (const float*)d_in[4];
  float* out = (float*)d_out;

  const size_t need = (size_t)N_EDGES * 128 * sizeof(float);  // 51.2 MB
  if (ws_size >= need) {
    float* proj = (float*)d_ws;
    // 6250 edge tiles, 1 wave each -> 1563 blocks of 256
    hipLaunchKernelGGL(edge_proj, dim3((E_TILES * 64 + 255) / 256), dim3(256), 0, stream,
                       hyperedge, W, bias, proj);
    hipLaunchKernelGGL(e2v_gather, dim3(4096), dim3(256), 0, stream,
                       hyper_node, aff, W, proj, out);
  } else {
    hipLaunchKernelGGL(e2v_mfma, dim3(4096), dim3(256), 0, stream,
                       hyperedge, hyper_node, aff, W, bias, out);
  }
}